// Round 4
// baseline (283.173 us; speedup 1.0000x reference)
//
#include <hip/hip_runtime.h>

typedef int i32x4 __attribute__((ext_vector_type(4)));

#define AS1 __attribute__((address_space(1)))
#define AS3 __attribute__((address_space(3)))

// ---------------------------------------------------------------------------
// Quantize kernel (UNCHANGED, verified 4 rounds). Blocks [0, M): per-token
// dynamic quant of x row r (4096 fp32 -> int8, scale sx[r] = rowmax/127).
// Blocks [M, M+wB): narrow w int32 (values 0..126, exact) -> int8.
// ---------------------------------------------------------------------------
__global__ __launch_bounds__(256) void quant_kernel(
    const float4* __restrict__ x, const int4* __restrict__ w,
    signed char* __restrict__ xq, signed char* __restrict__ wq,
    float* __restrict__ sx, int M, int Kq) {
  const int tid = threadIdx.x;
  if ((int)blockIdx.x < M) {
    const int r = blockIdx.x;
    float4 v[4];
    #pragma unroll
    for (int j = 0; j < 4; ++j) v[j] = x[(size_t)r * 1024 + tid * 4 + j];
    float m = 0.f;
    #pragma unroll
    for (int j = 0; j < 4; ++j)
      m = fmaxf(m, fmaxf(fmaxf(fabsf(v[j].x), fabsf(v[j].y)),
                         fmaxf(fabsf(v[j].z), fabsf(v[j].w))));
    #pragma unroll
    for (int off = 1; off < 64; off <<= 1) m = fmaxf(m, __shfl_xor(m, off));
    __shared__ float wmax[4];
    if ((tid & 63) == 0) wmax[tid >> 6] = m;
    __syncthreads();
    m = fmaxf(fmaxf(wmax[0], wmax[1]), fmaxf(wmax[2], wmax[3]));
    const float inv = (m > 0.f) ? 127.0f / m : 0.f;
    if (tid == 0) sx[r] = m * (1.0f / 127.0f);
    signed char q[16];
    #pragma unroll
    for (int j = 0; j < 4; ++j) {
      q[j * 4 + 0] = (signed char)__float2int_rn(v[j].x * inv);
      q[j * 4 + 1] = (signed char)__float2int_rn(v[j].y * inv);
      q[j * 4 + 2] = (signed char)__float2int_rn(v[j].z * inv);
      q[j * 4 + 3] = (signed char)__float2int_rn(v[j].w * inv);
    }
    ((int4*)xq)[(size_t)r * 256 + tid] = *(const int4*)q;
  } else {
    const int b = blockIdx.x - M;
    int4 v[4];
    #pragma unroll
    for (int j = 0; j < 4; ++j) v[j] = w[(size_t)b * 1024 + tid * 4 + j];
    signed char q[16];
    #pragma unroll
    for (int j = 0; j < 4; ++j) {
      q[j * 4 + 0] = (signed char)v[j].x; q[j * 4 + 1] = (signed char)v[j].y;
      q[j * 4 + 2] = (signed char)v[j].z; q[j * 4 + 3] = (signed char)v[j].w;
    }
    ((int4*)wq)[(size_t)b * 256 + tid] = *(const int4*)q;
  }
}

// ---------------------------------------------------------------------------
// C[M][N] = (Aq[M][K] . Bq[N][K]^T) * sx[M] * scaler[N]
//
// Round-4: FAT WAVES — raise MFMA:LDS-traffic ratio (the invariant across
// all four previous equal-time schedules).
//   block 256x256, 256 thr = 4 waves (2M x 2N), wave tile 128x128,
//   BK=64, mfma_i32_16x16x64_i8; 1 wave/SIMD (by design).
// Per K-tile per wave: 16 ds_read_b128 -> 64 independent MFMA (1:4 vs the
// previous 1:2.67); per CU per tile: MFMA pipe ~1306 cy vs LDS ~96KB
// (~750-1100 cy) — matrix pipe now dominates the traffic budget.
// Latency hiding: within-wave ILP (compiler's fine-grained lgkmcnt
// interleave of 16 reads among 64 MFMAs), not TLP.
// LDS: 3-deep ring x (sA 16KB + sB 16KB) = 96 KB. Tile t reads buf[t%3];
//   stages t+2 into buf[(t+2)%3]==buf[(t-1)%3], whose reads finished before
//   the end-of-tile-(t-1) barrier -> one barrier/tile suffices.
// vmcnt: 8 staging loads/tile; steady-state wait vmcnt(8) (t+2's loads in
//   flight, t+1 guaranteed landed). Never drains in main loop.
// Swizzle (64B rows, 4 x 16B slots): phys_slot = logical ^ ((row>>1)&3), on
//   pre-swizzled GLOBAL source (LDS dest linear, global_load_lds req) and on
//   the ds_read address -> 0 bank conflicts (HW-verified 3 rounds).
// No setprio: 1 wave/SIMD, nothing to arbitrate.
// ---------------------------------------------------------------------------
__global__ __launch_bounds__(256, 1) void gemm_i8_kernel(
    const signed char* __restrict__ A,   // [M][K] i8
    const signed char* __restrict__ B,   // [N][K] i8
    const float* __restrict__ sx,        // [M] x dequant scale
    const float* __restrict__ scaler,    // [N] weight scale
    float* __restrict__ C,               // [M][N] fp32
    int M, int N, int K)
{
  __shared__ signed char sA[3][256 * 64];   // 3 x 16 KB
  __shared__ signed char sB[3][256 * 64];   // 3 x 16 KB

  const int tid  = threadIdx.x;
  const int wave = tid >> 6;
  const int lane = tid & 63;
  const int bm = blockIdx.y << 8;           // 256-row M tile
  const int bn = blockIdx.x << 8;           // 256-col N tile

  const int wm = (wave >> 1) << 7;   // 0 or 128 : wave's M offset
  const int wn = (wave & 1) << 7;    // 0 or 128 : wave's N offset
  const int l15  = lane & 15;
  const int quad = lane >> 4;

  // Staging: 256 threads x 16B = 4KB per global_load_lds issue (64 rows).
  // Thread t: row = set*64 + (t>>2), phys 16B slot (t&3); logical k-group =
  // (t&3) ^ ((row>>1)&3). set*64 preserves (row>>1)&3 -> one kg for all sets.
  const int srow = tid >> 2;                      // 0..63
  const int kg = (tid & 3) ^ ((srow >> 1) & 3);
  const signed char* ga = A + (size_t)(bm + srow) * K + kg * 16;
  const signed char* gb = B + (size_t)(bn + srow) * K + kg * 16;
  const size_t rstep = (size_t)64 * K;            // +64 rows per set
  const int ldst = tid * 16;                      // linear LDS dest (4KB/set)

  // Fragment ds_read: row = (wm|wn) + frag*16 + l15, logical kgroup = quad,
  // phys = quad ^ ((l15>>1)&3)  (frag*16, wm, wn don't affect (row>>1)&3).
  const int pk   = (quad ^ ((l15 >> 1) & 3)) << 4;
  const int aoff = (wm + l15) * 64 + pk;    // + mi*1024 per fragment
  const int boff = (wn + l15) * 64 + pk;    // + ni*1024 per fragment

  i32x4 acc[8][8] = {};                     // 256 VGPR accumulator

  // STAGE(tt, sb): 8 global_load_lds — A rows [0,256) in 4 sets, B rows
  // [0,256) in 4 sets — into ring buffer sb.
#define STAGE(tt, sb) do { const size_t ko_ = (size_t)(tt) * 64;             \
    __builtin_amdgcn_global_load_lds((AS1 void*)(ga + ko_),             (AS3 void*)(&sA[sb][ldst]),         16, 0, 0); \
    __builtin_amdgcn_global_load_lds((AS1 void*)(ga + ko_ + rstep),     (AS3 void*)(&sA[sb][4096 + ldst]),  16, 0, 0); \
    __builtin_amdgcn_global_load_lds((AS1 void*)(ga + ko_ + 2 * rstep), (AS3 void*)(&sA[sb][8192 + ldst]),  16, 0, 0); \
    __builtin_amdgcn_global_load_lds((AS1 void*)(ga + ko_ + 3 * rstep), (AS3 void*)(&sA[sb][12288 + ldst]), 16, 0, 0); \
    __builtin_amdgcn_global_load_lds((AS1 void*)(gb + ko_),             (AS3 void*)(&sB[sb][ldst]),         16, 0, 0); \
    __builtin_amdgcn_global_load_lds((AS1 void*)(gb + ko_ + rstep),     (AS3 void*)(&sB[sb][4096 + ldst]),  16, 0, 0); \
    __builtin_amdgcn_global_load_lds((AS1 void*)(gb + ko_ + 2 * rstep), (AS3 void*)(&sB[sb][8192 + ldst]),  16, 0, 0); \
    __builtin_amdgcn_global_load_lds((AS1 void*)(gb + ko_ + 3 * rstep), (AS3 void*)(&sB[sb][12288 + ldst]), 16, 0, 0); } while (0)

  const int nt = K >> 6;                    // 64 K-tiles

  // Prologue: stage tiles 0,1 (16 loads); tile 0 ready when <=8 remain.
  STAGE(0, 0); STAGE(1, 1);
  asm volatile("s_waitcnt vmcnt(8)" ::: "memory");
  __builtin_amdgcn_s_barrier();
  __builtin_amdgcn_sched_barrier(0);

  int br = 0;                               // read buf  = t % 3
  int bs = 2;                               // stage buf = (t+2) % 3
  for (int t = 0; t < nt; ++t) {
    const signed char* la = sA[br];
    const signed char* lb = sB[br];

    if (t < nt - 2) STAGE(t + 2, bs);       // into buf[(t-1)%3] — safe (1 barrier ago)

    i32x4 av[8], bv[8];
    #pragma unroll
    for (int ni = 0; ni < 8; ++ni) bv[ni] = *(const i32x4*)&lb[boff + ni * 1024];
    #pragma unroll
    for (int mi = 0; mi < 8; ++mi) av[mi] = *(const i32x4*)&la[aoff + mi * 1024];

    #pragma unroll
    for (int mi = 0; mi < 8; ++mi)
      #pragma unroll
      for (int ni = 0; ni < 8; ++ni)
        acc[mi][ni] = __builtin_amdgcn_mfma_i32_16x16x64_i8(av[mi], bv[ni], acc[mi][ni], 0, 0, 0);

    // Tile boundary: guarantee tile t+1 landed; keep tile t+2's 8 in flight.
    if (t < nt - 2)        asm volatile("s_waitcnt vmcnt(8)" ::: "memory");
    else if (t == nt - 2)  asm volatile("s_waitcnt vmcnt(0)" ::: "memory");
    if (t < nt - 1) {
      __builtin_amdgcn_s_barrier();
      __builtin_amdgcn_sched_barrier(0);
    }
    br = (br == 2) ? 0 : br + 1;
    bs = (bs == 2) ? 0 : bs + 1;
  }
#undef STAGE

  // Epilogue: C/D layout col=lane&15 (N), row=quad*4+reg (M) — dtype-indep.
  #pragma unroll
  for (int mi = 0; mi < 8; ++mi) {
    const int gm0 = bm + wm + mi * 16 + quad * 4;
    float sr[4];
    #pragma unroll
    for (int r = 0; r < 4; ++r) sr[r] = sx[gm0 + r];
    #pragma unroll
    for (int ni = 0; ni < 8; ++ni) {
      const int gn = bn + wn + ni * 16 + l15;
      const float sc = scaler[gn];
      #pragma unroll
      for (int r = 0; r < 4; ++r)
        C[(size_t)(gm0 + r) * N + gn] = (float)acc[mi][ni][r] * sr[r] * sc;
    }
  }
}

extern "C" void kernel_launch(void* const* d_in, const int* in_sizes, int n_in,
                              void* d_out, int out_size, void* d_ws, size_t ws_size,
                              hipStream_t stream) {
  const float* x  = (const float*)d_in[0];          // [B,S,K] fp32
  const int*   w  = (const int*)d_in[1];            // [N,K] int32 (int8 range)
  const float* sc = (const float*)d_in[2];          // [N] fp32
  float* out = (float*)d_out;

  const int N = in_sizes[2];                        // 4096
  const int K = in_sizes[1] / N;                    // 4096
  const int M = in_sizes[0] / K;                    // 4096

  signed char* Aq = (signed char*)d_ws;             // [M][K] i8
  signed char* Bq = Aq + (size_t)M * K;             // [N][K] i8
  float* sx = (float*)(Bq + (size_t)N * K);         // [M] fp32

  const int wBlocks = (N * K) / (256 * 16);         // 16 elems/thread
  quant_kernel<<<M + wBlocks, 256, 0, stream>>>(
      (const float4*)x, (const int4*)w, Aq, Bq, sx, M, K / 16);

  dim3 grid(N / 256, M / 256);
  gemm_i8_kernel<<<grid, 256, 0, stream>>>(Aq, Bq, sx, sc, out, M, N, K);
}

// Round 5
// 246.216 us; speedup vs baseline: 1.1501x; 1.1501x over previous
//
#include <hip/hip_runtime.h>

typedef int i32x4  __attribute__((ext_vector_type(4)));
typedef int i32x16 __attribute__((ext_vector_type(16)));

#define AS1 __attribute__((address_space(1)))
#define AS3 __attribute__((address_space(3)))

// ---------------------------------------------------------------------------
// Quantize kernel — round-5: fully COALESCED (lane-consecutive) loads/stores.
// Same values, same rounding as the 4-round-verified version -> absmax must
// stay exactly 214. Thread t handles float4/int4 index j*256 + t (lane
// stride 16B, perfectly coalesced 1KB/instr) instead of the old 64B-stride
// pattern. Packs 4 int8 into one int32, coalesced 4B stores.
// Blocks [0,M): x rows (fp32 -> i8, scale sx[r] = rowmax/127).
// Blocks [M, M+wB): w int32 (values 0..126, exact) -> i8.
// ---------------------------------------------------------------------------
__global__ __launch_bounds__(256) void quant_kernel(
    const float4* __restrict__ x, const int4* __restrict__ w,
    signed char* __restrict__ xq, signed char* __restrict__ wq,
    float* __restrict__ sx, int M, int Kq) {
  const int tid = threadIdx.x;
  if ((int)blockIdx.x < M) {
    const int r = blockIdx.x;
    float4 v[4];
    #pragma unroll
    for (int j = 0; j < 4; ++j) v[j] = x[(size_t)r * 1024 + j * 256 + tid];
    float m = 0.f;
    #pragma unroll
    for (int j = 0; j < 4; ++j)
      m = fmaxf(m, fmaxf(fmaxf(fabsf(v[j].x), fabsf(v[j].y)),
                         fmaxf(fabsf(v[j].z), fabsf(v[j].w))));
    #pragma unroll
    for (int off = 1; off < 64; off <<= 1) m = fmaxf(m, __shfl_xor(m, off));
    __shared__ float wmax[4];
    if ((tid & 63) == 0) wmax[tid >> 6] = m;
    __syncthreads();
    m = fmaxf(fmaxf(wmax[0], wmax[1]), fmaxf(wmax[2], wmax[3]));
    const float inv = (m > 0.f) ? 127.0f / m : 0.f;
    if (tid == 0) sx[r] = m * (1.0f / 127.0f);
    int* out = (int*)xq;
    #pragma unroll
    for (int j = 0; j < 4; ++j) {
      const int q0 = __float2int_rn(v[j].x * inv) & 255;
      const int q1 = __float2int_rn(v[j].y * inv) & 255;
      const int q2 = __float2int_rn(v[j].z * inv) & 255;
      const int q3 = __float2int_rn(v[j].w * inv) & 255;
      out[(size_t)r * 1024 + j * 256 + tid] = q0 | (q1 << 8) | (q2 << 16) | (q3 << 24);
    }
  } else {
    const int b = blockIdx.x - M;
    int4 v[4];
    #pragma unroll
    for (int j = 0; j < 4; ++j) v[j] = w[(size_t)b * 1024 + j * 256 + tid];
    int* out = (int*)wq;
    #pragma unroll
    for (int j = 0; j < 4; ++j)
      out[(size_t)b * 1024 + j * 256 + tid] =
          (v[j].x & 255) | ((v[j].y & 255) << 8) | ((v[j].z & 255) << 16) | ((v[j].w & 255) << 24);
  }
}

// ---------------------------------------------------------------------------
// C[M][N] = (Aq[M][K] . Bq[N][K]^T) * sx[M] * scaler[N]
//
// Round-5: r3's best-measured structure (256x128 block, 4 waves, 2 blocks/CU,
// 3-deep ring, counted vmcnt(6), 1 barrier/tile, setprio) with the MFMA
// switched to mfma_i32_32x32x32_i8:
//   +12% pipe rate (4404 vs 3944 TOPS, m55 vs m16) and HALF the matrix
//   instructions (16/wave/K-tile instead of 32; same 12 ds_read_b128) ->
//   less issue pressure, more slots for ds_read/stage interleave.
// Fragment layouts (same family as the verified 16x16x64):
//   A: row = lane&31, k = (lane>>5)*16 + 0..15  (one i32x4 = 16 k-bytes)
//   B: col = lane&31, same k mapping
//   C/D: col = lane&31, row = (reg&3) + 8*(reg>>2) + 4*(lane>>5)  [m74/m101]
// Swizzle (64B rows, 4 x 16B slots): phys = logical ^ ((row>>1)&3) — same
// involution on the pre-swizzled GLOBAL source (LDS dest linear) and the
// ds_read address; bank coverage re-checked for 32-row fragments: uniform
// 8 words/bank -> conflict-free.
// Wave tile 128x64 = 4(M) x 2(N) fragments of 32x32; acc = 8 x i32x16 = 128.
// Ring liveness: tile t reads buf[t%3]; stages t+2 into buf[(t+2)%3] ==
// buf[(t-1)%3], read-complete one barrier ago -> 1 barrier/tile sufficient.
// ---------------------------------------------------------------------------
__global__ __launch_bounds__(256, 2) void gemm_i8_kernel(
    const signed char* __restrict__ A,   // [M][K] i8
    const signed char* __restrict__ B,   // [N][K] i8
    const float* __restrict__ sx,        // [M] x dequant scale
    const float* __restrict__ scaler,    // [N] weight scale
    float* __restrict__ C,               // [M][N] fp32
    int M, int N, int K)
{
  __shared__ signed char sA[3][256 * 64];   // 3 x 16 KB
  __shared__ signed char sB[3][128 * 64];   // 3 x  8 KB

  const int tid  = threadIdx.x;
  const int wave = tid >> 6;
  const int lane = tid & 63;
  const int bm = blockIdx.y << 8;           // 256-row M tile
  const int bn = blockIdx.x << 7;           // 128-col N tile

  const int wm = (wave >> 1) << 7;   // 0 or 128 : wave's M offset
  const int wn = (wave & 1) << 6;    // 0 or 64  : wave's N offset
  const int l31 = lane & 31;
  const int hi  = lane >> 5;         // k-half selector for 32x32 fragments

  // Staging (UNCHANGED, verified): thread t covers row set*64 + (t>>2),
  // phys 16B slot (t&3); logical k-group = (t&3) ^ ((row>>1)&3).
  const int srow = tid >> 2;                      // 0..63
  const int kg = (tid & 3) ^ ((srow >> 1) & 3);
  const signed char* ga = A + (size_t)(bm + srow) * K + kg * 16;
  const signed char* gb = B + (size_t)(bn + srow) * K + kg * 16;
  const size_t rstep = (size_t)64 * K;            // +64 rows per set
  const int ldst = tid * 16;                      // linear LDS dest

  // Fragment ds_read: row = (wm|wn) + mi*32 + l31 -> (row>>1)&3 = (l31>>1)&3
  // (wm, wn, mi*32 are multiples of 32). logical kgroup = ks*2 + hi,
  // phys = (ks*2 + hi) ^ ((l31>>1)&3);  pk(ks=1) = pk(ks=0) ^ 2.
  const int sw  = (l31 >> 1) & 3;
  const int pk0 = (hi ^ sw) << 4;           // ks=0 physical byte offset
  const int pk1 = ((2 | hi) ^ sw) << 4;     // ks=1
  const int arow = (wm + l31) * 64;         // + mi*2048 per fragment
  const int brow = (wn + l31) * 64;         // + ni*2048 per fragment

  i32x16 acc[4][2] = {};                    // 128 VGPR accumulator

  // STAGE(tt, sb): 6 global_load_lds — A rows [0,256) in 4 sets, B rows
  // [0,128) in 2 sets — into ring buffer sb.
#define STAGE(tt, sb) do { const size_t ko_ = (size_t)(tt) * 64;             \
    __builtin_amdgcn_global_load_lds((AS1 void*)(ga + ko_),             (AS3 void*)(&sA[sb][ldst]),         16, 0, 0); \
    __builtin_amdgcn_global_load_lds((AS1 void*)(ga + ko_ + rstep),     (AS3 void*)(&sA[sb][4096 + ldst]),  16, 0, 0); \
    __builtin_amdgcn_global_load_lds((AS1 void*)(ga + ko_ + 2 * rstep), (AS3 void*)(&sA[sb][8192 + ldst]),  16, 0, 0); \
    __builtin_amdgcn_global_load_lds((AS1 void*)(ga + ko_ + 3 * rstep), (AS3 void*)(&sA[sb][12288 + ldst]), 16, 0, 0); \
    __builtin_amdgcn_global_load_lds((AS1 void*)(gb + ko_),             (AS3 void*)(&sB[sb][ldst]),         16, 0, 0); \
    __builtin_amdgcn_global_load_lds((AS1 void*)(gb + ko_ + rstep),     (AS3 void*)(&sB[sb][4096 + ldst]),  16, 0, 0); } while (0)

  const int nt = K >> 6;                    // 64 K-tiles

  // Prologue: stage tiles 0,1 (12 loads); tile 0 ready when <=6 remain.
  STAGE(0, 0); STAGE(1, 1);
  asm volatile("s_waitcnt vmcnt(6)" ::: "memory");
  __builtin_amdgcn_s_barrier();
  __builtin_amdgcn_sched_barrier(0);

  int br = 0;                               // read buf  = t % 3
  int bs = 2;                               // stage buf = (t+2) % 3
  for (int t = 0; t < nt; ++t) {
    const signed char* la = sA[br];
    const signed char* lb = sB[br];

    if (t < nt - 2) STAGE(t + 2, bs);       // into buf[(t-1)%3] — safe (1 barrier ago)

    // 12 ds_read_b128: av[mi][ks], bv[ni][ks]
    i32x4 av[4][2], bv[2][2];
    #pragma unroll
    for (int ni = 0; ni < 2; ++ni) {
      bv[ni][0] = *(const i32x4*)&lb[brow + ni * 2048 + pk0];
      bv[ni][1] = *(const i32x4*)&lb[brow + ni * 2048 + pk1];
    }
    #pragma unroll
    for (int mi = 0; mi < 4; ++mi) {
      av[mi][0] = *(const i32x4*)&la[arow + mi * 2048 + pk0];
      av[mi][1] = *(const i32x4*)&la[arow + mi * 2048 + pk1];
    }

    __builtin_amdgcn_s_setprio(1);
    #pragma unroll
    for (int ks = 0; ks < 2; ++ks)
      #pragma unroll
      for (int mi = 0; mi < 4; ++mi)
        #pragma unroll
        for (int ni = 0; ni < 2; ++ni)
          acc[mi][ni] = __builtin_amdgcn_mfma_i32_32x32x32_i8(av[mi][ks], bv[ni][ks], acc[mi][ni], 0, 0, 0);
    __builtin_amdgcn_s_setprio(0);

    // Tile boundary: guarantee tile t+1 landed; keep tile t+2's 6 in flight.
    if (t < nt - 2)        asm volatile("s_waitcnt vmcnt(6)" ::: "memory");
    else if (t == nt - 2)  asm volatile("s_waitcnt vmcnt(0)" ::: "memory");
    if (t < nt - 1) {
      __builtin_amdgcn_s_barrier();
      __builtin_amdgcn_sched_barrier(0);
    }
    br = (br == 2) ? 0 : br + 1;
    bs = (bs == 2) ? 0 : bs + 1;
  }
#undef STAGE

  // Epilogue: 32x32 C/D layout — col = lane&31, row = (reg&3)+8*(reg>>2)+4*hi.
  float scn[2];
  #pragma unroll
  for (int ni = 0; ni < 2; ++ni) scn[ni] = scaler[bn + wn + ni * 32 + l31];
  #pragma unroll
  for (int mi = 0; mi < 4; ++mi) {
    const int gm0 = bm + wm + mi * 32 + hi * 4;
    #pragma unroll
    for (int rg = 0; rg < 4; ++rg) {        // reg>>2
      float sr[4];
      #pragma unroll
      for (int r = 0; r < 4; ++r) sr[r] = sx[gm0 + rg * 8 + r];
      #pragma unroll
      for (int ni = 0; ni < 2; ++ni) {
        const int gn = bn + wn + ni * 32 + l31;
        #pragma unroll
        for (int r = 0; r < 4; ++r)
          C[(size_t)(gm0 + rg * 8 + r) * N + gn] =
              (float)acc[mi][ni][rg * 4 + r] * sr[r] * scn[ni];
      }
    }
  }
}

extern "C" void kernel_launch(void* const* d_in, const int* in_sizes, int n_in,
                              void* d_out, int out_size, void* d_ws, size_t ws_size,
                              hipStream_t stream) {
  const float* x  = (const float*)d_in[0];          // [B,S,K] fp32
  const int*   w  = (const int*)d_in[1];            // [N,K] int32 (int8 range)
  const float* sc = (const float*)d_in[2];          // [N] fp32
  float* out = (float*)d_out;

  const int N = in_sizes[2];                        // 4096
  const int K = in_sizes[1] / N;                    // 4096
  const int M = in_sizes[0] / K;                    // 4096

  signed char* Aq = (signed char*)d_ws;             // [M][K] i8
  signed char* Bq = Aq + (size_t)M * K;             // [N][K] i8
  float* sx = (float*)(Bq + (size_t)N * K);         // [M] fp32

  const int wBlocks = (N * K) / (256 * 16);         // 16 elems/thread
  quant_kernel<<<M + wBlocks, 256, 0, stream>>>(
      (const float4*)x, (const int4*)w, Aq, Bq, sx, M, K / 16);

  dim3 grid(N / 128, M / 256);
  gemm_i8_kernel<<<grid, 256, 0, stream>>>(Aq, Bq, sx, sc, out, M, N, K);
}

// Round 6
// 240.563 us; speedup vs baseline: 1.1771x; 1.0235x over previous
//
#include <hip/hip_runtime.h>

typedef int i32x4 __attribute__((ext_vector_type(4)));

#define AS1 __attribute__((address_space(1)))
#define AS3 __attribute__((address_space(3)))

// ---------------------------------------------------------------------------
// Quantize kernel (r5 version, VERIFIED: absmax identical, ~6us faster than
// the strided original). Fully coalesced lane-consecutive loads/stores.
// Blocks [0,M): x rows (fp32 -> i8, scale sx[r] = rowmax/127).
// Blocks [M, M+wB): w int32 (values 0..126, exact) -> i8.
// ---------------------------------------------------------------------------
__global__ __launch_bounds__(256) void quant_kernel(
    const float4* __restrict__ x, const int4* __restrict__ w,
    signed char* __restrict__ xq, signed char* __restrict__ wq,
    float* __restrict__ sx, int M, int Kq) {
  const int tid = threadIdx.x;
  if ((int)blockIdx.x < M) {
    const int r = blockIdx.x;
    float4 v[4];
    #pragma unroll
    for (int j = 0; j < 4; ++j) v[j] = x[(size_t)r * 1024 + j * 256 + tid];
    float m = 0.f;
    #pragma unroll
    for (int j = 0; j < 4; ++j)
      m = fmaxf(m, fmaxf(fmaxf(fabsf(v[j].x), fabsf(v[j].y)),
                         fmaxf(fabsf(v[j].z), fabsf(v[j].w))));
    #pragma unroll
    for (int off = 1; off < 64; off <<= 1) m = fmaxf(m, __shfl_xor(m, off));
    __shared__ float wmax[4];
    if ((tid & 63) == 0) wmax[tid >> 6] = m;
    __syncthreads();
    m = fmaxf(fmaxf(wmax[0], wmax[1]), fmaxf(wmax[2], wmax[3]));
    const float inv = (m > 0.f) ? 127.0f / m : 0.f;
    if (tid == 0) sx[r] = m * (1.0f / 127.0f);
    int* out = (int*)xq;
    #pragma unroll
    for (int j = 0; j < 4; ++j) {
      const int q0 = __float2int_rn(v[j].x * inv) & 255;
      const int q1 = __float2int_rn(v[j].y * inv) & 255;
      const int q2 = __float2int_rn(v[j].z * inv) & 255;
      const int q3 = __float2int_rn(v[j].w * inv) & 255;
      out[(size_t)r * 1024 + j * 256 + tid] = q0 | (q1 << 8) | (q2 << 16) | (q3 << 24);
    }
  } else {
    const int b = blockIdx.x - M;
    int4 v[4];
    #pragma unroll
    for (int j = 0; j < 4; ++j) v[j] = w[(size_t)b * 1024 + j * 256 + tid];
    int* out = (int*)wq;
    #pragma unroll
    for (int j = 0; j < 4; ++j)
      out[(size_t)b * 1024 + j * 256 + tid] =
          (v[j].x & 255) | ((v[j].y & 255) << 8) | ((v[j].z & 255) << 16) | ((v[j].w & 255) << 24);
  }
}

// ---------------------------------------------------------------------------
// C[M][N] = (Aq[M][K] . Bq[N][K]^T) * sx[M] * scaler[N]
//
// Round-6 = r3's gemm VERBATIM (best measured: 87-88us, 0 bank conflicts)
// + T1 XCD-aware bijective block swizzle (grid = 512 = 64*8, so the simple
// form is bijective). Everything else byte-identical to the verified r3.
//   tile 256(M) x 128(N), 256 thr = 4 waves (2M x 2N), per-wave 128x64 out,
//   LDS = 3-deep ring x (sA 16KB + sB 8KB) = 72 KB -> TWO blocks per CU.
//   mfma_i32_16x16x64_i8 (16x16 family: fragment+swizzle HW-verified 0-conflict).
// Ring liveness: tile t reads buf[t%3]; stages t+2 into buf[(t+2)%3] ==
//   buf[(t-1)%3], read-complete one barrier ago -> 1 barrier/tile sufficient.
// vmcnt: 6 loads/tile; steady-state vmcnt(6) keeps t+2's loads in flight,
//   guarantees t+1 landed. Never drains in the main loop.
// Swizzle (64B rows, 4 x 16B slots): phys_slot = logical ^ ((row>>1)&3), on
//   the pre-swizzled GLOBAL source (LDS dest linear, global_load_lds req)
//   and on the ds_read address -> 0 bank conflicts (HW-verified r3).
// ---------------------------------------------------------------------------
__global__ __launch_bounds__(256, 2) void gemm_i8_kernel(
    const signed char* __restrict__ A,   // [M][K] i8
    const signed char* __restrict__ B,   // [N][K] i8
    const float* __restrict__ sx,        // [M] x dequant scale
    const float* __restrict__ scaler,    // [N] weight scale
    float* __restrict__ C,               // [M][N] fp32
    int M, int N, int K)
{
  __shared__ signed char sA[3][256 * 64];   // 3 x 16 KB
  __shared__ signed char sB[3][128 * 64];   // 3 x  8 KB

  const int tid  = threadIdx.x;
  const int wave = tid >> 6;
  const int lane = tid & 63;

  // T1: XCD-aware bijective swizzle. Dispatch round-robins linear block id
  // across the 8 XCDs; remap so each XCD owns a contiguous chunk of the
  // (by,bx) grid -> neighboring tiles (sharing A/B panels) land on the same
  // XCD's L2. nwg = 512, 512 % 8 == 0 -> swz = (lin%8)*64 + lin/8 bijective.
  const int lin = (int)(blockIdx.y * gridDim.x + blockIdx.x);
  const int swz = (lin & 7) * 64 + (lin >> 3);
  const int bxs = swz & 31;                 // 32 N-tiles
  const int bys = swz >> 5;                 // 16 M-tiles
  const int bm = bys << 8;                  // 256-row M tile
  const int bn = bxs << 7;                  // 128-col N tile

  const int wm = (wave >> 1) << 7;   // 0 or 128 : wave's M offset
  const int wn = (wave & 1) << 6;    // 0 or 64  : wave's N offset
  const int l15  = lane & 15;
  const int quad = lane >> 4;

  // Staging: thread t covers row set*64 + (t>>2), phys 16B slot (t&3);
  // logical k-group = (t&3) ^ ((row>>1)&3). set*64 preserves (row>>1)&3,
  // so one kg serves all sets.
  const int srow = tid >> 2;                      // 0..63
  const int kg = (tid & 3) ^ ((srow >> 1) & 3);
  const signed char* ga = A + (size_t)(bm + srow) * K + kg * 16;
  const signed char* gb = B + (size_t)(bn + srow) * K + kg * 16;
  const size_t rstep = (size_t)64 * K;            // +64 rows per set
  const int ldst = tid * 16;                      // linear LDS dest (4KB/set)

  // Fragment ds_read: row = (wm|wn) + frag*16 + l15, logical kgroup = quad,
  // phys = quad ^ ((l15>>1)&3)  (frag*16, wm, wn don't affect (row>>1)&3).
  const int pk   = (quad ^ ((l15 >> 1) & 3)) << 4;
  const int aoff = (wm + l15) * 64 + pk;    // + mi*1024 per fragment
  const int boff = (wn + l15) * 64 + pk;    // + ni*1024 per fragment

  i32x4 acc[8][4] = {};

  // STAGE(tt, sb): 6 global_load_lds — A rows [0,256) in 4 sets, B rows
  // [0,128) in 2 sets — into ring buffer sb.
#define STAGE(tt, sb) do { const size_t ko_ = (size_t)(tt) * 64;             \
    __builtin_amdgcn_global_load_lds((AS1 void*)(ga + ko_),             (AS3 void*)(&sA[sb][ldst]),         16, 0, 0); \
    __builtin_amdgcn_global_load_lds((AS1 void*)(ga + ko_ + rstep),     (AS3 void*)(&sA[sb][4096 + ldst]),  16, 0, 0); \
    __builtin_amdgcn_global_load_lds((AS1 void*)(ga + ko_ + 2 * rstep), (AS3 void*)(&sA[sb][8192 + ldst]),  16, 0, 0); \
    __builtin_amdgcn_global_load_lds((AS1 void*)(ga + ko_ + 3 * rstep), (AS3 void*)(&sA[sb][12288 + ldst]), 16, 0, 0); \
    __builtin_amdgcn_global_load_lds((AS1 void*)(gb + ko_),             (AS3 void*)(&sB[sb][ldst]),         16, 0, 0); \
    __builtin_amdgcn_global_load_lds((AS1 void*)(gb + ko_ + rstep),     (AS3 void*)(&sB[sb][4096 + ldst]),  16, 0, 0); } while (0)

  const int nt = K >> 6;                    // 64 K-tiles

  // Prologue: stage tiles 0,1 (12 loads); tile 0 ready when <=6 remain.
  STAGE(0, 0); STAGE(1, 1);
  asm volatile("s_waitcnt vmcnt(6)" ::: "memory");
  __builtin_amdgcn_s_barrier();
  __builtin_amdgcn_sched_barrier(0);

  int br = 0;                               // read buf  = t % 3
  int bs = 2;                               // stage buf = (t+2) % 3
  for (int t = 0; t < nt; ++t) {
    const signed char* la = sA[br];
    const signed char* lb = sB[br];

    if (t < nt - 2) STAGE(t + 2, bs);       // into buf[(t-1)%3] — safe (1 barrier ago)

    i32x4 av[8], bv[4];
    #pragma unroll
    for (int ni = 0; ni < 4; ++ni) bv[ni] = *(const i32x4*)&lb[boff + ni * 1024];
    #pragma unroll
    for (int mi = 0; mi < 8; ++mi) av[mi] = *(const i32x4*)&la[aoff + mi * 1024];

    __builtin_amdgcn_s_setprio(1);
    #pragma unroll
    for (int mi = 0; mi < 8; ++mi)
      #pragma unroll
      for (int ni = 0; ni < 4; ++ni)
        acc[mi][ni] = __builtin_amdgcn_mfma_i32_16x16x64_i8(av[mi], bv[ni], acc[mi][ni], 0, 0, 0);
    __builtin_amdgcn_s_setprio(0);

    // Tile boundary: guarantee tile t+1 landed; keep tile t+2's 6 in flight.
    if (t < nt - 2)        asm volatile("s_waitcnt vmcnt(6)" ::: "memory");
    else if (t == nt - 2)  asm volatile("s_waitcnt vmcnt(0)" ::: "memory");
    if (t < nt - 1) {
      __builtin_amdgcn_s_barrier();
      __builtin_amdgcn_sched_barrier(0);
    }
    br = (br == 2) ? 0 : br + 1;
    bs = (bs == 2) ? 0 : bs + 1;
  }
#undef STAGE

  // Epilogue: C/D layout col=lane&15 (N), row=quad*4+reg (M) — dtype-indep.
  #pragma unroll
  for (int mi = 0; mi < 8; ++mi) {
    const int gm0 = bm + wm + mi * 16 + quad * 4;
    float sr[4];
    #pragma unroll
    for (int r = 0; r < 4; ++r) sr[r] = sx[gm0 + r];
    #pragma unroll
    for (int ni = 0; ni < 4; ++ni) {
      const int gn = bn + wn + ni * 16 + l15;
      const float sc = scaler[gn];
      #pragma unroll
      for (int r = 0; r < 4; ++r)
        C[(size_t)(gm0 + r) * N + gn] = (float)acc[mi][ni][r] * sr[r] * sc;
    }
  }
}

extern "C" void kernel_launch(void* const* d_in, const int* in_sizes, int n_in,
                              void* d_out, int out_size, void* d_ws, size_t ws_size,
                              hipStream_t stream) {
  const float* x  = (const float*)d_in[0];          // [B,S,K] fp32
  const int*   w  = (const int*)d_in[1];            // [N,K] int32 (int8 range)
  const float* sc = (const float*)d_in[2];          // [N] fp32
  float* out = (float*)d_out;

  const int N = in_sizes[2];                        // 4096
  const int K = in_sizes[1] / N;                    // 4096
  const int M = in_sizes[0] / K;                    // 4096

  signed char* Aq = (signed char*)d_ws;             // [M][K] i8
  signed char* Bq = Aq + (size_t)M * K;             // [N][K] i8
  float* sx = (float*)(Bq + (size_t)N * K);         // [M] fp32

  const int wBlocks = (N * K) / (256 * 16);         // 16 elems/thread
  quant_kernel<<<M + wBlocks, 256, 0, stream>>>(
      (const float4*)x, (const int4*)w, Aq, Bq, sx, M, K / 16);

  dim3 grid(N / 128, M / 256);
  gemm_i8_kernel<<<grid, 256, 0, stream>>>(Aq, Bq, sx, sc, out, M, N, K);
}